// Round 10
// baseline (362.982 us; speedup 1.0000x reference)
//
#include <hip/hip_runtime.h>
#include <cstdint>
#include <cstddef>

// Problem constants (Qwen3VLMoeTextExperts): E=8, H=2048, I=768, T=B*S=4096
#define NE 8
#define NH 2048
#define NI 768
#define NT 4096
#define NK2 6144   // NE*NI : K of second GEMM

typedef __bf16 bf16x8 __attribute__((ext_vector_type(8)));
typedef float f32x4 __attribute__((ext_vector_type(4)));
typedef unsigned short u16x8 __attribute__((ext_vector_type(8)));

__device__ __forceinline__ unsigned short f2bf(float f) {
  unsigned int u = __builtin_bit_cast(unsigned int, f);
  u += 0x7fffu + ((u >> 16) & 1u);   // round-to-nearest-even
  return (unsigned short)(u >> 16);
}

// async global->LDS, 16B per lane (dest must be linear: base + lane*16).
__device__ __forceinline__ void gload_lds16(const void* g, void* s) {
  __builtin_amdgcn_global_load_lds(
      (const __attribute__((address_space(1))) unsigned int*)g,
      (__attribute__((address_space(3))) unsigned int*)s, 16, 0, 0);
}

// ---------------- convert f32 -> bf16 (vectorized x8) ----------------
__global__ __launch_bounds__(256) void k_cvt(const float* __restrict__ in,
                                             unsigned short* __restrict__ out,
                                             long n) {
  long i = ((long)blockIdx.x * blockDim.x + threadIdx.x) * 8;
  if (i >= n) return;
  float4 f0 = *reinterpret_cast<const float4*>(in + i);
  float4 f1 = *reinterpret_cast<const float4*>(in + i + 4);
  u16x8 o;
  o[0] = f2bf(f0.x); o[1] = f2bf(f0.y); o[2] = f2bf(f0.z); o[3] = f2bf(f0.w);
  o[4] = f2bf(f1.x); o[5] = f2bf(f1.y); o[6] = f2bf(f1.z); o[7] = f2bf(f1.w);
  *reinterpret_cast<u16x8*>(out + i) = o;
}

// ------------- transpose + convert: out[b*oBS + perm(c)*oCS + r] = in[b][r][c] -------------
// mode 0: perm = identity. mode 1 (gate_up): interleave gate/up at 16-col
// granularity: gate col c -> (c>>4)*32 + (c&15); up col c -> (c>>4)*32 + 16 + (c&15).
__global__ __launch_bounds__(256) void k_transpose_cvt(
    const float* __restrict__ in, unsigned short* __restrict__ out,
    int R, int C, long inBS, long outBS, int outCS, int mode) {
  __shared__ float tile[32][33];
  const int b = blockIdx.z;
  const int r0 = blockIdx.y * 32, c0 = blockIdx.x * 32;
  const int tx = threadIdx.x, ty = threadIdx.y;
  const float* ib = in + (long)b * inBS;
#pragma unroll
  for (int d = 0; d < 4; d++)
    tile[ty + d * 8][tx] = ib[(long)(r0 + ty + d * 8) * C + c0 + tx];
  __syncthreads();
#pragma unroll
  for (int d = 0; d < 4; d++) {
    int c = c0 + ty + d * 8;   // original out-major index
    int r = r0 + tx;           // out minor index (coalesced)
    int orow;
    if (mode == 1) {
      int z = (c >= NI) ? 1 : 0;
      int cc = c - z * NI;
      orow = ((cc >> 4) << 5) + (z << 4) + (cc & 15);
    } else {
      orow = c;
    }
    out[(long)b * outBS + (long)orow * outCS + r] = f2bf(tile[tx][ty + d * 8]);
  }
}

// ==================== READ-AHEAD PIPELINE GEMMs ====================
// Key structure (both GEMMs): 4 LDS buffers, BK=32. In region kt a wave:
//   - MFMAs tile kt from fragments ALREADY IN REGISTERS (read in region kt-1)
//     -> matrix pipe has no lgkmcnt dependency on this region's LDS reads;
//   - reads tile kt+1's fragments (certified: stage(kt+1) retired by the
//     counted vmcnt at end of region kt-1 + barrier = collective);
//   - issues stage(kt+3) into buf[(kt+3)&3] (last read in region kt-2,
//     >=2 barriers ago);
//   - end: vmcnt(NSTG) retires stage(kt+2) (2-region cover ~2400 cyc);
//     s_barrier.
// LDS layout per tile (paired-row): logical (r,k) k<32 -> phys row pr=r>>1
// (64B-wide... 128B rows of 8 16B-chunks), chunk pcl=(r&1)*4+(k>>3), stored
// swizzled pc=pcl^(pr&7). Staging keeps linear LDS dest (chunk c -> decode
// r,kc from c) with per-thread global source; frag reads use the same XOR.
// Uniform 8-lanes-per-bank-group => conflict-free b128 reads and writes.
// Fragment register sets double-buffered with static E/O naming (rule #20).

// ==================== GEMM1: 256x256, BK=32, 4 buffers (128 KiB) ====================
// 8 waves: wr=wave>>2 (M), wc=wave&3 (N); per-wave out 128x64 (M-interleaved).
// Per region: 12 ds_read_b128, 4 gload_lds, 32 MFMA, 1 vmcnt, 1 barrier.
__global__ __launch_bounds__(512, 1) void k_gemm1(
    const unsigned short* __restrict__ Xb,    // [NT][NH] bf16
    const unsigned short* __restrict__ W1t,   // [NE][1536(perm)][NH] bf16
    const float* __restrict__ rw,             // [NT][NE]
    unsigned short* __restrict__ inter) {     // [NT][NK2] bf16
  __shared__ unsigned short lds[4][16384];    // [buf][A 0..8191 | B 8192..16383]

  const int e = blockIdx.z;
  const int t0 = blockIdx.y * 256;
  const int bn = blockIdx.x;
  const int tid = threadIdx.x;
  const int lane = tid & 63, wave = tid >> 6;
  const int wr = wave >> 2, wc = wave & 3;
  const int fr = lane & 15, fq = lane >> 4;
  const int nkt = NH / 32;                   // 64

  const unsigned short* Bg = W1t + (size_t)e * (2 * NI) * NH;

  // staging chunk descriptors: chunk c -> pr=c>>3, pc=c&7, pcl=pc^(pr&7),
  // logical row r=(pr<<1)|(pcl>>2), k-chunk kc=pcl&3.
  int r0c, k0c, r1c, k1c;
  {
    int c = tid, pr = c >> 3, pc = c & 7, pcl = pc ^ (pr & 7);
    r0c = (pr << 1) | (pcl >> 2); k0c = pcl & 3;
    c = tid + 512; pr = c >> 3; pc = c & 7; pcl = pc ^ (pr & 7);
    r1c = (pr << 1) | (pcl >> 2); k1c = pcl & 3;
  }
  const unsigned short* sA0 = Xb + (size_t)(t0 + r0c) * NH + k0c * 8;
  const unsigned short* sA1 = Xb + (size_t)(t0 + r1c) * NH + k1c * 8;
  const unsigned short* sB0 = Bg + (size_t)(bn * 256 + r0c) * NH + k0c * 8;
  const unsigned short* sB1 = Bg + (size_t)(bn * 256 + r1c) * NH + k1c * 8;
  const int dst0 = tid * 8, dst1 = tid * 8 + 4096;

#define STG1(T) do { \
    unsigned short* L_ = lds[(T) & 3]; const size_t ko_ = (size_t)(T) * 32; \
    gload_lds16(sA0 + ko_, L_ + dst0); \
    gload_lds16(sA1 + ko_, L_ + dst1); \
    gload_lds16(sB0 + ko_, L_ + 8192 + dst0); \
    gload_lds16(sB1 + ko_, L_ + 8192 + dst1); \
  } while (0)

  f32x4 acc[8][4];
#pragma unroll
  for (int i = 0; i < 8; ++i)
#pragma unroll
    for (int j = 0; j < 4; ++j) acc[i][j] = (f32x4){0.f, 0.f, 0.f, 0.f};

  // fragment read offsets (ushort units)
  int aoff[8], boff[4];
#pragma unroll
  for (int m = 0; m < 8; ++m) {
    const int rA = (m >> 2) * 128 + wr * 64 + (m & 3) * 16 + fr;
    const int pr = rA >> 1;
    const int pcs = (((rA & 1) << 2) | fq) ^ (pr & 7);
    aoff[m] = pr * 64 + pcs * 8;
  }
#pragma unroll
  for (int j = 0; j < 4; ++j) {
    const int rB = (j >> 1) * 128 + wc * 32 + (j & 1) * 16 + fr;
    const int pr = rB >> 1;
    const int pcs = (((rB & 1) << 2) | fq) ^ (pr & 7);
    boff[j] = 8192 + pr * 64 + pcs * 8;
  }

#define READ1(T, F) do { \
    const unsigned short* L_ = lds[(T) & 3]; \
    _Pragma("unroll") \
    for (int m = 0; m < 8; ++m) F[m] = *reinterpret_cast<const bf16x8*>(L_ + aoff[m]); \
    _Pragma("unroll") \
    for (int j = 0; j < 4; ++j) F[8 + j] = *reinterpret_cast<const bf16x8*>(L_ + boff[j]); \
  } while (0)

#define REGION1(KT, CUR, NXT) do { \
    const int kt_ = (KT); \
    if (kt_ + 1 < nkt) READ1(kt_ + 1, NXT); \
    if (kt_ + 3 < nkt) STG1(kt_ + 3); \
    _Pragma("unroll") \
    for (int m = 0; m < 8; ++m) \
      _Pragma("unroll") \
      for (int j = 0; j < 4; ++j) \
        acc[m][j] = __builtin_amdgcn_mfma_f32_16x16x32_bf16(CUR[m], CUR[8 + j], acc[m][j], 0, 0, 0); \
    if (kt_ + 3 < nkt)      { asm volatile("s_waitcnt vmcnt(4)" ::: "memory"); } \
    else if (kt_ + 2 < nkt) { asm volatile("s_waitcnt vmcnt(0)" ::: "memory"); } \
    if (kt_ + 1 < nkt)      { asm volatile("s_barrier" ::: "memory"); } \
  } while (0)

  // prologue: stage tiles 0,1,2; retire 0,1; barrier; read tile 0.
  STG1(0); STG1(1); STG1(2);
  asm volatile("s_waitcnt vmcnt(4)" ::: "memory");
  asm volatile("s_barrier" ::: "memory");

  bf16x8 fE[12], fO[12];
  READ1(0, fE);
  for (int i = 0; i < nkt / 2; ++i) {
    REGION1(2 * i, fE, fO);
    REGION1(2 * i + 1, fO, fE);
  }
  asm volatile("s_waitcnt vmcnt(0)" ::: "memory");
#undef REGION1
#undef READ1
#undef STG1

  // epilogue: silu(gate)*up*rw -> bf16.  acc[i][2p]=gate, acc[i][2p+1]=up for
  // inter col (within expert) = (p*4 + wc)*16 + fr; token row from rA(i).
#pragma unroll
  for (int i = 0; i < 8; ++i) {
    const int trow = t0 + (i >> 2) * 128 + wr * 64 + (i & 3) * 16 + fq * 4;
#pragma unroll
    for (int r = 0; r < 4; ++r) {
      const int t = trow + r;
      const float rwv = rw[(size_t)t * NE + e];
#pragma unroll
      for (int p = 0; p < 2; ++p) {
        float g = acc[i][2 * p][r];
        float u = acc[i][2 * p + 1][r];
        float s = g / (1.f + __expf(-g));  // silu
        const int col = bn * 128 + (p * 4 + wc) * 16 + fr;
        inter[(size_t)t * NK2 + e * NI + col] = f2bf(rwv * u * s);
      }
    }
  }
}

// ==================== GEMM2: 256x128, BK=32, 4 buffers (96 KiB) ====================
// 8 waves: wr=wave>>1 (4 M-slices of 64), wc=wave&1 (2 N-slices of 64).
// Per region: 8 ds_read_b128, 3 gload_lds, 16 MFMA, 1 vmcnt, 1 barrier.
__global__ __launch_bounds__(512, 1) void k_gemm2(
    const unsigned short* __restrict__ inter,  // [NT][NK2] bf16
    const unsigned short* __restrict__ W2t,    // [NH][NK2] bf16
    float* __restrict__ out) {                 // [NT][NH] f32
  __shared__ unsigned short lds[4][12288];     // [buf][A 0..8191 | B 8192..12287]

  const int t0 = blockIdx.y * 256;
  const int h0 = blockIdx.x * 128;
  const int tid = threadIdx.x;
  const int lane = tid & 63, wave = tid >> 6;
  const int wr = wave >> 1, wc = wave & 1;
  const int fr = lane & 15, fq = lane >> 4;
  const int nkt = NK2 / 32;                  // 192

  int r0c, k0c, r1c, k1c;
  {
    int c = tid, pr = c >> 3, pc = c & 7, pcl = pc ^ (pr & 7);
    r0c = (pr << 1) | (pcl >> 2); k0c = pcl & 3;
    c = tid + 512; pr = c >> 3; pc = c & 7; pcl = pc ^ (pr & 7);
    r1c = (pr << 1) | (pcl >> 2); k1c = pcl & 3;
  }
  const unsigned short* sA0 = inter + (size_t)(t0 + r0c) * NK2 + k0c * 8;
  const unsigned short* sA1 = inter + (size_t)(t0 + r1c) * NK2 + k1c * 8;
  const unsigned short* sB0 = W2t + (size_t)(h0 + r0c) * NK2 + k0c * 8;
  const int dst0 = tid * 8, dst1 = tid * 8 + 4096;

#define STG2(T) do { \
    unsigned short* L_ = lds[(T) & 3]; const size_t ko_ = (size_t)(T) * 32; \
    gload_lds16(sA0 + ko_, L_ + dst0); \
    gload_lds16(sA1 + ko_, L_ + dst1); \
    gload_lds16(sB0 + ko_, L_ + 8192 + dst0); \
  } while (0)

  f32x4 acc[4][4];
#pragma unroll
  for (int i = 0; i < 4; ++i)
#pragma unroll
    for (int j = 0; j < 4; ++j) acc[i][j] = (f32x4){0.f, 0.f, 0.f, 0.f};

  int aoff[4], boff[4];
#pragma unroll
  for (int m = 0; m < 4; ++m) {
    const int rA = wr * 64 + m * 16 + fr;
    const int pr = rA >> 1;
    const int pcs = (((rA & 1) << 2) | fq) ^ (pr & 7);
    aoff[m] = pr * 64 + pcs * 8;
  }
#pragma unroll
  for (int j = 0; j < 4; ++j) {
    const int rB = wc * 64 + j * 16 + fr;
    const int pr = rB >> 1;
    const int pcs = (((rB & 1) << 2) | fq) ^ (pr & 7);
    boff[j] = 8192 + pr * 64 + pcs * 8;
  }

#define READ2(T, F) do { \
    const unsigned short* L_ = lds[(T) & 3]; \
    _Pragma("unroll") \
    for (int m = 0; m < 4; ++m) F[m] = *reinterpret_cast<const bf16x8*>(L_ + aoff[m]); \
    _Pragma("unroll") \
    for (int j = 0; j < 4; ++j) F[4 + j] = *reinterpret_cast<const bf16x8*>(L_ + boff[j]); \
  } while (0)

#define REGION2(KT, CUR, NXT) do { \
    const int kt_ = (KT); \
    if (kt_ + 1 < nkt) READ2(kt_ + 1, NXT); \
    if (kt_ + 3 < nkt) STG2(kt_ + 3); \
    _Pragma("unroll") \
    for (int m = 0; m < 4; ++m) \
      _Pragma("unroll") \
      for (int j = 0; j < 4; ++j) \
        acc[m][j] = __builtin_amdgcn_mfma_f32_16x16x32_bf16(CUR[m], CUR[4 + j], acc[m][j], 0, 0, 0); \
    if (kt_ + 3 < nkt)      { asm volatile("s_waitcnt vmcnt(3)" ::: "memory"); } \
    else if (kt_ + 2 < nkt) { asm volatile("s_waitcnt vmcnt(0)" ::: "memory"); } \
    if (kt_ + 1 < nkt)      { asm volatile("s_barrier" ::: "memory"); } \
  } while (0)

  STG2(0); STG2(1); STG2(2);
  asm volatile("s_waitcnt vmcnt(3)" ::: "memory");
  asm volatile("s_barrier" ::: "memory");

  bf16x8 fE[8], fO[8];
  READ2(0, fE);
  for (int i = 0; i < nkt / 2; ++i) {
    REGION2(2 * i, fE, fO);
    REGION2(2 * i + 1, fO, fE);
  }
  asm volatile("s_waitcnt vmcnt(0)" ::: "memory");
#undef REGION2
#undef READ2
#undef STG2

  const int rowBase = t0 + wr * 64 + fq * 4;
#pragma unroll
  for (int i = 0; i < 4; ++i)
#pragma unroll
    for (int j = 0; j < 4; ++j)
#pragma unroll
      for (int r = 0; r < 4; ++r)
        out[(size_t)(rowBase + i * 16 + r) * NH + h0 + wc * 64 + j * 16 + fr] =
            acc[i][j][r];
}

extern "C" void kernel_launch(void* const* d_in, const int* in_sizes, int n_in,
                              void* d_out, int out_size, void* d_ws, size_t ws_size,
                              hipStream_t stream) {
  const float* x = (const float*)d_in[0];    // [NT][NH]
  const float* rw = (const float*)d_in[1];   // [NT][NE]
  // d_in[2] router_indices: unused by reference (dense all-experts)
  const float* w1 = (const float*)d_in[3];   // [NE][NH][2*NI]
  const float* w2 = (const float*)d_in[4];   // [NE][NI][NH]
  float* out = (float*)d_out;

  char* ws = (char*)d_ws;
  // ws layout (bf16): Xb 16MB | W1t 48MB | W2t 24MB | inter 48MB  = 136 MiB
  unsigned short* Xb = (unsigned short*)ws;                               // [NT][NH]
  unsigned short* W1t = (unsigned short*)(ws + 16777216);                 // [NE][1536perm][NH]
  unsigned short* W2t = (unsigned short*)(ws + 16777216 + 50331648);      // [NH][NK2]
  unsigned short* inter = (unsigned short*)(ws + 16777216 + 50331648 + 25165824); // [NT][NK2]

  // 1) convert x
  k_cvt<<<dim3((NT * NH) / (256 * 8)), dim3(256), 0, stream>>>(x, Xb, (long)NT * NH);
  // 2) W1 [E][H][2I] -> W1t [E][perm(2I)][H], gate/up 16-interleaved
  k_transpose_cvt<<<dim3((2 * NI) / 32, NH / 32, NE), dim3(32, 8), 0, stream>>>(
      w1, W1t, NH, 2 * NI, (long)NH * 2 * NI, (long)2 * NI * NH, NH, 1);
  // 3) W2 [E][I][H] -> W2t [H][E*I]
  k_transpose_cvt<<<dim3(NH / 32, NI / 32, NE), dim3(32, 8), 0, stream>>>(
      w2, W2t, NI, NH, (long)NI * NH, (long)NI, NK2, 0);
  // 4) GEMM1 fused silu/up/rw -> inter (read-ahead pipeline, 256x256, BK=32)
  k_gemm1<<<dim3((2 * NI) / 256, NT / 256, NE), dim3(512), 0, stream>>>(Xb, W1t, rw, inter);
  // 5) GEMM2 -> out (read-ahead pipeline, 256x128, BK=32)
  k_gemm2<<<dim3(NH / 128, NT / 256), dim3(512), 0, stream>>>(inter, W2t, out);
}